// Round 1
// baseline (134.174 us; speedup 1.0000x reference)
//
#include <hip/hip_runtime.h>

// CrumbReconstructor: for each 8-float block of x, find nearest codebook row
// (squared Euclidean over 256 rows of length 8), output that row.
//
// x:      [64*14*14*512] fp32  -> 802816 key-blocks of 8
// memory: [256*8] fp32 codebook
// out:    same shape as x, fp32
//
// Strategy: codebook + row norms in LDS (9 KB), broadcast reads; each thread
// handles T=2 key-blocks; distances in fp32 matching the reference formula's
// evaluation order so argmin matches numpy on all but exact-tie cases.

#define LBLK 8      // memblock length
#define NROW 256    // codebook rows
#define TPK 2       // key-blocks per thread
#define BLOCK 256   // threads per workgroup

__global__ __launch_bounds__(BLOCK) void crumb_kernel(
    const float* __restrict__ x,
    const float* __restrict__ mem,
    float* __restrict__ out,
    int nblocks)
{
    __shared__ float s_mem[NROW * LBLK];   // 8 KB, rows contiguous (32 B apart, 16B-aligned)
    __shared__ float s_norm[NROW];         // 1 KB

    const int tid = threadIdx.x;

    // --- stage codebook: thread t loads row t, computes its norm ---
    {
        const float4* g = (const float4*)mem;
        float4 a = g[tid * 2 + 0];
        float4 b = g[tid * 2 + 1];
        ((float4*)s_mem)[tid * 2 + 0] = a;
        ((float4*)s_mem)[tid * 2 + 1] = b;
        // mimic numpy: elementwise square (rounded), then 8-wide tree sum
        float q0 = a.x * a.x, q1 = a.y * a.y, q2 = a.z * a.z, q3 = a.w * a.w;
        float q4 = b.x * b.x, q5 = b.y * b.y, q6 = b.z * b.z, q7 = b.w * b.w;
        s_norm[tid] = ((q0 + q1) + (q2 + q3)) + ((q4 + q5) + (q6 + q7));
    }
    __syncthreads();

    const long base = (long)blockIdx.x * (BLOCK * TPK) + tid;

    float k[TPK][LBLK];
    float knorm[TPK];
    long  kb[TPK];
    bool  valid[TPK];

    #pragma unroll
    for (int t = 0; t < TPK; ++t) {
        long b0 = base + (long)t * BLOCK;
        valid[t] = (b0 < (long)nblocks);
        kb[t] = valid[t] ? b0 : 0;
        const float4* g = (const float4*)(x + kb[t] * LBLK);
        float4 a = g[0], b = g[1];
        k[t][0] = a.x; k[t][1] = a.y; k[t][2] = a.z; k[t][3] = a.w;
        k[t][4] = b.x; k[t][5] = b.y; k[t][6] = b.z; k[t][7] = b.w;
        float q0 = a.x * a.x, q1 = a.y * a.y, q2 = a.z * a.z, q3 = a.w * a.w;
        float q4 = b.x * b.x, q5 = b.y * b.y, q6 = b.z * b.z, q7 = b.w * b.w;
        knorm[t] = ((q0 + q1) + (q2 + q3)) + ((q4 + q5) + (q6 + q7));
    }

    float best[TPK];
    int   bidx[TPK];
    #pragma unroll
    for (int t = 0; t < TPK; ++t) { best[t] = 3.4e38f; bidx[t] = 0; }

    // --- score all 256 rows; LDS reads are wave-uniform (broadcast) ---
    #pragma unroll 4
    for (int m = 0; m < NROW; ++m) {
        float4 a = ((const float4*)s_mem)[m * 2 + 0];
        float4 b = ((const float4*)s_mem)[m * 2 + 1];
        float nrm = s_norm[m];
        #pragma unroll
        for (int t = 0; t < TPK; ++t) {
            // sequential FMA dot (sgemm-like order)
            float dot = k[t][0] * a.x;
            dot = fmaf(k[t][1], a.y, dot);
            dot = fmaf(k[t][2], a.z, dot);
            dot = fmaf(k[t][3], a.w, dot);
            dot = fmaf(k[t][4], b.x, dot);
            dot = fmaf(k[t][5], b.y, dot);
            dot = fmaf(k[t][6], b.z, dot);
            dot = fmaf(k[t][7], b.w, dot);
            // d = (knorm - 2*dot) + mnorm ; 2*dot is exact, so fmaf(dot,-2,knorm)
            // bit-matches (knorm - 2*dot) with one rounding.
            float d = fmaf(dot, -2.0f, knorm[t]) + nrm;
            // strict < : first index wins ties (matches jnp.argmin)
            if (d < best[t]) { best[t] = d; bidx[t] = m; }
        }
    }

    // --- gather winning rows from LDS, store ---
    #pragma unroll
    for (int t = 0; t < TPK; ++t) {
        if (valid[t]) {
            float4* o = (float4*)(out + kb[t] * LBLK);
            o[0] = ((const float4*)s_mem)[bidx[t] * 2 + 0];
            o[1] = ((const float4*)s_mem)[bidx[t] * 2 + 1];
        }
    }
}

extern "C" void kernel_launch(void* const* d_in, const int* in_sizes, int n_in,
                              void* d_out, int out_size, void* d_ws, size_t ws_size,
                              hipStream_t stream) {
    const float* x   = (const float*)d_in[0];
    const float* mem = (const float*)d_in[1];
    float* out = (float*)d_out;

    int n = in_sizes[0];            // total x elements
    int nblocks = n / LBLK;         // key-blocks
    int grid = (nblocks + BLOCK * TPK - 1) / (BLOCK * TPK);

    hipLaunchKernelGGL(crumb_kernel, dim3(grid), dim3(BLOCK), 0, stream,
                       x, mem, out, nblocks);
}